// Round 2
// baseline (665.756 us; speedup 1.0000x reference)
//
#include <hip/hip_runtime.h>

typedef unsigned short u16;
typedef unsigned int   u32;
typedef __bf16 bf16x8 __attribute__((ext_vector_type(8)));
typedef float  f32x4  __attribute__((ext_vector_type(4)));
typedef u32    u32x4  __attribute__((ext_vector_type(4)));

#define NS 256              // samples (M)
#define KF 10000            // features (K)
#define KP 10048            // padded K (multiple of 64)
#define NO 15000            // outputs (N)
#define NP 15104            // padded N = 118*128
#define BM 256
#define BN 128
#define BK 32
#define KHALF (KP/2)        // 5024
#define NSTEPS (KHALF/BK)   // 157
#define COVR 150
#define NA 100

// ---------------- prep: BatchNorm affine + fp32 -> bf16 hi/lo split ----------------
__global__ void k_prep_x(const float* __restrict__ x, const float* __restrict__ gamma,
                         const float* __restrict__ beta, const float* __restrict__ rmean,
                         const float* __restrict__ rvar,
                         u16* __restrict__ xnh, u16* __restrict__ xnl)
{
    int k = blockIdx.x * 256 + threadIdx.x;
    int s = blockIdx.y;
    if (k >= KP) return;
    float v = 0.0f;
    if (k < KF) {
        float xv = x[(size_t)s * KF + k];
        v = (xv - rmean[k]) * (gamma[k] * rsqrtf(rvar[k] + 1e-5f)) + beta[k];
    }
    u32 bits = __float_as_uint(v);
    u32 hb   = bits & 0xffff0000u;              // truncate -> hi bf16
    float lo = v - __uint_as_float(hb);         // exact residual
    xnh[(size_t)s * KP + k] = (u16)(hb >> 16);
    xnl[(size_t)s * KP + k] = (u16)(__float_as_uint(lo) >> 16);
}

__device__ __forceinline__ void split_pack(float v0, float v1, u32& hp, u32& lp)
{
    u32 b0 = __float_as_uint(v0), b1 = __float_as_uint(v1);
    u32 h0 = b0 & 0xffff0000u,   h1 = b1 & 0xffff0000u;
    hp = (h0 >> 16) | h1;
    float r0 = v0 - __uint_as_float(h0);
    float r1 = v1 - __uint_as_float(h1);
    lp = (__float_as_uint(r0) >> 16) | (__float_as_uint(r1) & 0xffff0000u);
}

__device__ __forceinline__ void gload16(const u16* g, u16* l)
{
    __builtin_amdgcn_global_load_lds(
        (const __attribute__((address_space(1))) void*)g,
        (__attribute__((address_space(3))) void*)l, 16, 0, 0);
}

// ---------------- GEMM: Yp[ks] = Xn * W^T (3-term bf16 split), split-K=2 ----------------
// 512 thr (8 waves, wave tile 64x64), BM=256 x BN=128, BK=32, double-buffered LDS (96KB).
// A: global_load_lds width-16, pre-swizzled global src -> linear LDS (swizzled reads).
// W: reg-staged fp32 -> split_pack -> ds_write, issued one K-step early.
// One raw s_barrier per step; counted vmcnt(2) keeps next-step loads in flight (T3/T4).
__global__ __launch_bounds__(512, 1) void k_gemm(
    const u16* __restrict__ xnh, const u16* __restrict__ xnl,
    const float* __restrict__ W, float* __restrict__ Yp)
{
    __shared__ u16 Ah[2][BM * BK];
    __shared__ u16 Al[2][BM * BK];
    __shared__ u16 Bh[2][BN * BK];
    __shared__ u16 Bl[2][BN * BK];

    const int t    = threadIdx.x;
    const int wv   = t >> 6;
    const int n0   = blockIdx.x * BN;
    const int ks   = blockIdx.y;
    const int kbeg = ks * KHALF;

    // A staging: LDS slot t (rows 0-127) and t+512 (rows 128-255), global chunk pre-swizzled
    const int rA0 = t >> 2;
    const int rA1 = rA0 + 128;
    const int uA  = t & 3;
    const int cA0 = uA ^ ((rA0 >> 1) & 3);
    const int cA1 = uA ^ ((rA1 >> 1) & 3);
    const size_t eA0 = (size_t)rA0 * KP + cA0 * 8;
    const size_t eA1 = (size_t)rA1 * KP + cA1 * 8;

    // W staging: row rB (output n0+rB), chunk pre-swizzled
    const int rB  = t >> 2;
    const int cB  = (t & 3) ^ ((rB >> 1) & 3);
    const int oW  = n0 + rB;
    const bool oOk = (oW < NO);
    const size_t eW = (size_t)(oOk ? oW : 0) * KF + cB * 8;

    // compute-side lane constants
    const int lane = t & 63;
    const int wm   = (t >> 6) & 3;  // 4 M-groups of 64
    const int wn   = t >> 8;        // 2 N-groups of 64
    const int l15  = lane & 15;
    const int lc   = lane >> 4;
    const int q    = (l15 >> 1) & 3;
    const int eoff = l15 * BK + ((lc ^ q) << 3);   // swizzled element offset

    f32x4 acc[4][4];
#pragma unroll
    for (int m = 0; m < 4; ++m)
#pragma unroll
        for (int n = 0; n < 4; ++n) { acc[m][n][0]=0.f; acc[m][n][1]=0.f; acc[m][n][2]=0.f; acc[m][n][3]=0.f; }

    auto issueA = [&](int nb, int k1) {
        gload16(xnh + eA0 + k1, Ah[nb] + (wv << 9));
        gload16(xnh + eA1 + k1, Ah[nb] + 4096 + (wv << 9));
        gload16(xnl + eA0 + k1, Al[nb] + (wv << 9));
        gload16(xnl + eA1 + k1, Al[nb] + 4096 + (wv << 9));
    };
    auto stageB = [&](int nb, f32x4 w0, f32x4 w1, float msk) {
        w0 *= msk; w1 *= msk;
        u32 h0,p0,h1,p1,h2,p2,h3,p3;
        split_pack(w0[0], w0[1], h0, p0);
        split_pack(w0[2], w0[3], h1, p1);
        split_pack(w1[0], w1[1], h2, p2);
        split_pack(w1[2], w1[3], h3, p3);
        u32x4 hv, lv; hv[0]=h0; hv[1]=h1; hv[2]=h2; hv[3]=h3; lv[0]=p0; lv[1]=p1; lv[2]=p2; lv[3]=p3;
        ((u32x4*)Bh[nb])[t] = hv;
        ((u32x4*)Bl[nb])[t] = lv;
    };

    // prologue: A(0) -> buf0 (DMA), W(0) -> regs -> LDS buf0
    {
        const int k0 = kbeg;
        issueA(0, k0);
        asm volatile("" ::: "memory");   // pin A(0) issue before anything else
        const bool okk = oOk && (k0 + cB * 8 + 8 <= KF);
        const size_t wofs = okk ? (eW + k0) : 0;
        f32x4 w0 = *(const f32x4*)(W + wofs);
        f32x4 w1 = *(const f32x4*)(W + wofs + 4);
        stageB(0, w0, w1, okk ? 1.f : 0.f);   // compiler inserts exact vmcnt for w0/w1
    }

#pragma unroll 1
    for (int step = 0; step < NSTEPS - 1; ++step) {
        const int p  = step & 1;
        const int nb = p ^ 1;
        const int k1 = kbeg + (step + 1) * BK;

        // issue next W (regs); stays in flight across the barrier
        const bool okk = oOk && (k1 + cB * 8 + 8 <= KF);
        const size_t wofs = okk ? (eW + k1) : 0;
        f32x4 nw0 = *(const f32x4*)(W + wofs);
        f32x4 nw1 = *(const f32x4*)(W + wofs + 4);
        const float nmsk = okk ? 1.f : 0.f;

        // A(step) landed (oldest 4 of [A(step)x4, W(step+1)x2]); B(step) ds_writes flushed
        asm volatile("s_waitcnt vmcnt(2) lgkmcnt(0)" ::: "memory");
        __builtin_amdgcn_s_barrier();
        asm volatile("" ::: "memory");

        // issue next A DMA into the other buffer (safe: everyone passed the barrier)
        issueA(nb, k1);
        asm volatile("" ::: "memory");

        // compute on buf p
        const u16* AhL = Ah[p]; const u16* AlL = Al[p];
        const u16* BhL = Bh[p]; const u16* BlL = Bl[p];
        bf16x8 fah[4], fal[4], fbh[4], fbl[4];
#pragma unroll
        for (int m = 0; m < 4; ++m) {
            const int off = (wm * 64 + m * 16) * BK + eoff;
            fah[m] = *(const bf16x8*)(AhL + off);
            fal[m] = *(const bf16x8*)(AlL + off);
        }
#pragma unroll
        for (int n = 0; n < 4; ++n) {
            const int off = (wn * 64 + n * 16) * BK + eoff;
            fbh[n] = *(const bf16x8*)(BhL + off);
            fbl[n] = *(const bf16x8*)(BlL + off);
        }
        __builtin_amdgcn_s_setprio(1);
#pragma unroll
        for (int m = 0; m < 4; ++m)
#pragma unroll
            for (int n = 0; n < 4; ++n) {
                acc[m][n] = __builtin_amdgcn_mfma_f32_16x16x32_bf16(fah[m], fbh[n], acc[m][n], 0, 0, 0);
                acc[m][n] = __builtin_amdgcn_mfma_f32_16x16x32_bf16(fah[m], fbl[n], acc[m][n], 0, 0, 0);
                acc[m][n] = __builtin_amdgcn_mfma_f32_16x16x32_bf16(fal[m], fbh[n], acc[m][n], 0, 0, 0);
            }
        __builtin_amdgcn_s_setprio(0);

        // write next W tile into the other buffer (read next step, after barrier)
        stageB(nb, nw0, nw1, nmsk);
    }

    // last step (buf (NSTEPS-1)&1 == 0)
    asm volatile("s_waitcnt vmcnt(0) lgkmcnt(0)" ::: "memory");
    __builtin_amdgcn_s_barrier();
    asm volatile("" ::: "memory");
    {
        const u16* AhL = Ah[0]; const u16* AlL = Al[0];
        const u16* BhL = Bh[0]; const u16* BlL = Bl[0];
        bf16x8 fah[4], fal[4], fbh[4], fbl[4];
#pragma unroll
        for (int m = 0; m < 4; ++m) {
            const int off = (wm * 64 + m * 16) * BK + eoff;
            fah[m] = *(const bf16x8*)(AhL + off);
            fal[m] = *(const bf16x8*)(AlL + off);
        }
#pragma unroll
        for (int n = 0; n < 4; ++n) {
            const int off = (wn * 64 + n * 16) * BK + eoff;
            fbh[n] = *(const bf16x8*)(BhL + off);
            fbl[n] = *(const bf16x8*)(BlL + off);
        }
#pragma unroll
        for (int m = 0; m < 4; ++m)
#pragma unroll
            for (int n = 0; n < 4; ++n) {
                acc[m][n] = __builtin_amdgcn_mfma_f32_16x16x32_bf16(fah[m], fbh[n], acc[m][n], 0, 0, 0);
                acc[m][n] = __builtin_amdgcn_mfma_f32_16x16x32_bf16(fah[m], fbl[n], acc[m][n], 0, 0, 0);
                acc[m][n] = __builtin_amdgcn_mfma_f32_16x16x32_bf16(fal[m], fbh[n], acc[m][n], 0, 0, 0);
            }
    }

    // epilogue: C/D layout col = lane&15, row = (lane>>4)*4 + reg
    const int rowb = wm * 64 + lc * 4;
    const int colb = n0 + wn * 64 + l15;
#pragma unroll
    for (int m = 0; m < 4; ++m)
#pragma unroll
        for (int n = 0; n < 4; ++n) {
            const size_t base = ((size_t)(ks * NS + rowb + m * 16)) * NP + colb + n * 16;
            Yp[base]          = acc[m][n][0];
            Yp[base + NP]     = acc[m][n][1];
            Yp[base + 2*NP]   = acc[m][n][2];
            Yp[base + 3*NP]   = acc[m][n][3];
        }
}

// ---------------- reduce split-K partials + bias + relu ----------------
__global__ void k_reduce(const float* __restrict__ Yp, const float* __restrict__ bias,
                         float* __restrict__ Y)
{
    int o = blockIdx.x * 256 + threadIdx.x;
    int s = blockIdx.y;
    if (o >= NO) return;
    size_t i = (size_t)s * NP + o;
    float v = Yp[i] + Yp[(size_t)NS * NP + i] + bias[o];
    Y[i] = fmaxf(v, 0.0f);
}

// ---------------- per-sample: cov -> Cholesky -> w = A^-1 1 / (1^T A^-1 1) ----------------
__global__ __launch_bounds__(256) void k_solve(const float* __restrict__ Y, float* __restrict__ out)
{
    __shared__ float Ash[104 * 113];
    __shared__ float Msh[30 * 112];
    __shared__ float mu[104];
    __shared__ float dg[104];
    __shared__ float fv[104];
    __shared__ float fs[104];
    __shared__ float gv[104];
    __shared__ float gs[104];
    __shared__ float red[8];

    const int s = blockIdx.x;
    const int t = threadIdx.x;
    const float* Ys = Y + (size_t)s * NP;

    // column means
    if (t < NA) {
        float a = 0.f;
        for (int r = 0; r < COVR; ++r) a += Ys[r * NA + t];
        mu[t] = a * (1.0f / COVR);
    }
    __syncthreads();

    // A = m^T m / 149, built in 5 chunks of 30 rows; thread (ai,bj) owns 8x7 tile
    const int ai = t >> 4;
    const int bj = t & 15;
    float acc[8][7];
#pragma unroll
    for (int i = 0; i < 8; ++i)
#pragma unroll
        for (int j = 0; j < 7; ++j) acc[i][j] = 0.f;

    for (int c = 0; c < 5; ++c) {
        for (int idx = t; idx < 30 * 112; idx += 256) {
            int r = idx / 112, j = idx - r * 112;
            float v = 0.f;
            if (j < NA) v = Ys[(c * 30 + r) * NA + j] - mu[j];
            Msh[idx] = v;
        }
        __syncthreads();
        if (ai < 13) {
            for (int r = 0; r < 30; ++r) {
                float mi[8], mj[7];
#pragma unroll
                for (int i = 0; i < 8; ++i) mi[i] = Msh[r * 112 + ai * 8 + i];
#pragma unroll
                for (int j = 0; j < 7; ++j) mj[j] = Msh[r * 112 + bj * 7 + j];
#pragma unroll
                for (int i = 0; i < 8; ++i)
#pragma unroll
                    for (int j = 0; j < 7; ++j) acc[i][j] += mi[i] * mj[j];
            }
        }
        __syncthreads();
    }
    if (ai < 13) {
#pragma unroll
        for (int i = 0; i < 8; ++i)
#pragma unroll
            for (int j = 0; j < 7; ++j)
                Ash[(ai * 8 + i) * 113 + (bj * 7 + j)] = acc[i][j] * (1.0f / 149.0f);
    }
    __syncthreads();

    // in-place Cholesky (lower), 2 barriers/column; diag kept in dg[]
    for (int j = 0; j < NA; ++j) {
        const float dv = sqrtf(Ash[j * 113 + j]);   // all threads read (no write to this slot here)
        const float dinv = 1.0f / dv;
        if (t == 0) dg[j] = dv;
        if (t > j && t < NA) Ash[t * 113 + j] *= dinv;
        __syncthreads();
        if (t > j && t < NA) {
            const float ckj = Ash[t * 113 + j];
            for (int i = t; i < NA; ++i)
                Ash[i * 113 + t] -= Ash[i * 113 + j] * ckj;
        }
        __syncthreads();
    }

    // forward solve L fs = 1   (1 barrier/step; solution in fs[], running vector fv[])
    if (t < NA) fv[t] = 1.0f;
    __syncthreads();
    for (int j = 0; j < NA; ++j) {
        const float yj = fv[j] / dg[j];
        if (t == j) fs[j] = yj;
        if (t > j && t < NA) fv[t] -= Ash[t * 113 + j] * yj;
        __syncthreads();
    }
    // backward solve L^T gs = fs
    if (t < NA) gv[t] = fs[t];
    __syncthreads();
    for (int j = NA - 1; j >= 0; --j) {
        const float uj = gv[j] / dg[j];
        if (t == j) gs[j] = uj;
        if (t < j) gv[t] -= Ash[j * 113 + t] * uj;
        __syncthreads();
    }

    // normalize: w = u / sum(u)
    const float uval = (t < NA) ? gs[t] : 0.f;
    float v = uval;
    for (int off = 32; off > 0; off >>= 1) v += __shfl_down(v, off);
    if ((t & 63) == 0) red[t >> 6] = v;
    __syncthreads();
    const float tot = red[0] + red[1] + red[2] + red[3];
    const float inv = 1.0f / tot;
    if (t < NA) out[s * NA + t] = uval * inv;
}

// ---------------- launcher ----------------
extern "C" void kernel_launch(void* const* d_in, const int* in_sizes, int n_in,
                              void* d_out, int out_size, void* d_ws, size_t ws_size,
                              hipStream_t stream)
{
    const float* x     = (const float*)d_in[0];
    const float* gamma = (const float*)d_in[1];
    const float* beta  = (const float*)d_in[2];
    const float* rm    = (const float*)d_in[3];
    const float* rv    = (const float*)d_in[4];
    const float* W     = (const float*)d_in[5];
    const float* b     = (const float*)d_in[6];
    float* out = (float*)d_out;

    char* ws = (char*)d_ws;
    u16*   xnh = (u16*)ws;                              // 256*10048*2  = 5,144,576 B
    u16*   xnl = (u16*)(ws + 5144576);                  // 5,144,576 B
    float* Yp  = (float*)(ws + 10289152);               // 2*256*15104*4 = 30,932,992 B
    float* Y   = (float*)(ws + 41222144);               // 256*15104*4 = 15,466,496 B
    (void)in_sizes; (void)n_in; (void)out_size; (void)ws_size;

    k_prep_x<<<dim3(40, NS), 256, 0, stream>>>(x, gamma, beta, rm, rv, xnh, xnl);
    k_gemm  <<<dim3(NP / BN, 2), 512, 0, stream>>>(xnh, xnl, W, Yp);
    k_reduce<<<dim3((NO + 255) / 256, NS), 256, 0, stream>>>(Yp, b, Y);
    k_solve <<<dim3(NS), 256, 0, stream>>>(Y, out);
}

// Round 3
// 656.299 us; speedup vs baseline: 1.0144x; 1.0144x over previous
//
#include <hip/hip_runtime.h>

typedef unsigned short u16;
typedef unsigned int   u32;
typedef __bf16 bf16x8 __attribute__((ext_vector_type(8)));
typedef float  f32x4  __attribute__((ext_vector_type(4)));
typedef u32    u32x4  __attribute__((ext_vector_type(4)));

#define NS 256              // samples (M)
#define KF 10000            // features (K)
#define KP 10048            // padded K (multiple of 64)
#define NO 15000            // outputs (N)
#define NP 15104            // padded N = 118*128
#define BM 256
#define BN 128
#define BK 32
#define KHALF (KP/2)        // 5024
#define NSTEPS (KHALF/BK)   // 157
#define COVR 150
#define NA 100

// ---------------- prep: BatchNorm affine + fp32 -> bf16 hi/lo split ----------------
__global__ void k_prep_x(const float* __restrict__ x, const float* __restrict__ gamma,
                         const float* __restrict__ beta, const float* __restrict__ rmean,
                         const float* __restrict__ rvar,
                         u16* __restrict__ xnh, u16* __restrict__ xnl)
{
    int k = blockIdx.x * 256 + threadIdx.x;
    int s = blockIdx.y;
    if (k >= KP) return;
    float v = 0.0f;
    if (k < KF) {
        float xv = x[(size_t)s * KF + k];
        v = (xv - rmean[k]) * (gamma[k] * rsqrtf(rvar[k] + 1e-5f)) + beta[k];
    }
    u32 bits = __float_as_uint(v);
    u32 hb   = bits & 0xffff0000u;              // truncate -> hi bf16
    float lo = v - __uint_as_float(hb);         // exact residual
    xnh[(size_t)s * KP + k] = (u16)(hb >> 16);
    xnl[(size_t)s * KP + k] = (u16)(__float_as_uint(lo) >> 16);
}

__device__ __forceinline__ void split_pack(float v0, float v1, u32& hp, u32& lp)
{
    u32 b0 = __float_as_uint(v0), b1 = __float_as_uint(v1);
    u32 h0 = b0 & 0xffff0000u,   h1 = b1 & 0xffff0000u;
    hp = (h0 >> 16) | h1;
    float r0 = v0 - __uint_as_float(h0);
    float r1 = v1 - __uint_as_float(h1);
    lp = (__float_as_uint(r0) >> 16) | (__float_as_uint(r1) & 0xffff0000u);
}

__device__ __forceinline__ void gload16(const u16* g, u16* l)
{
    __builtin_amdgcn_global_load_lds(
        (const __attribute__((address_space(1))) void*)g,
        (__attribute__((address_space(3))) void*)l, 16, 0, 0);
}

// ---------------- GEMM: Yp[ks] = Xn * W^T (3-term bf16 split), split-K=2 ----------------
// 512 thr (8 waves, wave tile 64x64), BM=256 x BN=128, BK=32, double-buffered LDS (96KB).
// 3 phases/step (one per split term): {ds_read; s_barrier; setprio; 16 MFMA; setprio}.
// Counted vmcnt(2) at step top only; A-DMA + next-W loads stay in flight across phases.
__global__ __launch_bounds__(512, 1) void k_gemm(
    const u16* __restrict__ xnh, const u16* __restrict__ xnl,
    const float* __restrict__ W, float* __restrict__ Yp)
{
    __shared__ u16 Ah[2][BM * BK];
    __shared__ u16 Al[2][BM * BK];
    __shared__ u16 Bh[2][BN * BK];
    __shared__ u16 Bl[2][BN * BK];

    const int t    = threadIdx.x;
    const int wv   = t >> 6;
    const int n0   = blockIdx.x * BN;
    const int ks   = blockIdx.y;
    const int kbeg = ks * KHALF;

    // A staging: LDS slot t (rows 0-127) and t+512 (rows 128-255), global chunk pre-swizzled
    const int rA0 = t >> 2;
    const int rA1 = rA0 + 128;
    const int uA  = t & 3;
    const int cA0 = uA ^ ((rA0 >> 1) & 3);
    const int cA1 = uA ^ ((rA1 >> 1) & 3);
    const size_t eA0 = (size_t)rA0 * KP + cA0 * 8;
    const size_t eA1 = (size_t)rA1 * KP + cA1 * 8;

    // W staging: row rB (output n0+rB), chunk pre-swizzled
    const int rB  = t >> 2;
    const int cB  = (t & 3) ^ ((rB >> 1) & 3);
    const int oW  = n0 + rB;
    const bool oOk = (oW < NO);
    const size_t eW = (size_t)(oOk ? oW : 0) * KF + cB * 8;

    // compute-side lane constants
    const int lane = t & 63;
    const int wm   = (t >> 6) & 3;  // 4 M-groups of 64
    const int wn   = t >> 8;        // 2 N-groups of 64
    const int l15  = lane & 15;
    const int lc   = lane >> 4;
    const int q    = (l15 >> 1) & 3;
    const int eoff = l15 * BK + ((lc ^ q) << 3);   // swizzled element offset

    f32x4 acc[4][4];
#pragma unroll
    for (int m = 0; m < 4; ++m)
#pragma unroll
        for (int n = 0; n < 4; ++n) { acc[m][n][0]=0.f; acc[m][n][1]=0.f; acc[m][n][2]=0.f; acc[m][n][3]=0.f; }

    auto issueA = [&](int nb, int k1) {
        gload16(xnh + eA0 + k1, Ah[nb] + (wv << 9));
        gload16(xnh + eA1 + k1, Ah[nb] + 4096 + (wv << 9));
        gload16(xnl + eA0 + k1, Al[nb] + (wv << 9));
        gload16(xnl + eA1 + k1, Al[nb] + 4096 + (wv << 9));
    };
    auto stageB = [&](int nb, f32x4 w0, f32x4 w1, float msk) {
        w0 *= msk; w1 *= msk;
        u32 h0,p0,h1,p1,h2,p2,h3,p3;
        split_pack(w0[0], w0[1], h0, p0);
        split_pack(w0[2], w0[3], h1, p1);
        split_pack(w1[0], w1[1], h2, p2);
        split_pack(w1[2], w1[3], h3, p3);
        u32x4 hv, lv; hv[0]=h0; hv[1]=h1; hv[2]=h2; hv[3]=h3; lv[0]=p0; lv[1]=p1; lv[2]=p2; lv[3]=p3;
        ((u32x4*)Bh[nb])[t] = hv;
        ((u32x4*)Bl[nb])[t] = lv;
    };

    // prologue: A(0) -> buf0 (DMA), W(0) -> regs -> LDS buf0
    {
        const int k0 = kbeg;
        issueA(0, k0);
        asm volatile("" ::: "memory");
        const bool okk = oOk && (k0 + cB * 8 + 8 <= KF);
        const size_t wofs = okk ? (eW + k0) : 0;
        f32x4 w0 = *(const f32x4*)(W + wofs);
        f32x4 w1 = *(const f32x4*)(W + wofs + 4);
        stageB(0, w0, w1, okk ? 1.f : 0.f);
    }

#pragma unroll 1
    for (int step = 0; step < NSTEPS - 1; ++step) {
        const int p  = step & 1;
        const int nb = p ^ 1;
        const int k1 = kbeg + (step + 1) * BK;

        // issue next W (regs); stays in flight across barriers
        const bool okk = oOk && (k1 + cB * 8 + 8 <= KF);
        const size_t wofs = okk ? (eW + k1) : 0;
        f32x4 nw0 = *(const f32x4*)(W + wofs);
        f32x4 nw1 = *(const f32x4*)(W + wofs + 4);
        const float nmsk = okk ? 1.f : 0.f;

        // A(step) landed (oldest 4 of [A(step)x4, W(step+1)x2]); B(step) ds_writes flushed
        asm volatile("s_waitcnt vmcnt(2) lgkmcnt(0)" ::: "memory");
        __builtin_amdgcn_s_barrier();
        asm volatile("" ::: "memory");

        // issue next A DMA into the other buffer
        issueA(nb, k1);
        asm volatile("" ::: "memory");

        const u16* AhL = Ah[p]; const u16* AlL = Al[p];
        const u16* BhL = Bh[p]; const u16* BlL = Bl[p];

        // ---- phase 1: hh ----
        bf16x8 fah[4], fbh[4];
#pragma unroll
        for (int m = 0; m < 4; ++m) fah[m] = *(const bf16x8*)(AhL + (wm * 64 + m * 16) * BK + eoff);
#pragma unroll
        for (int n = 0; n < 4; ++n) fbh[n] = *(const bf16x8*)(BhL + (wn * 64 + n * 16) * BK + eoff);
        __builtin_amdgcn_s_barrier();
        __builtin_amdgcn_s_setprio(1);
#pragma unroll
        for (int m = 0; m < 4; ++m)
#pragma unroll
            for (int n = 0; n < 4; ++n)
                acc[m][n] = __builtin_amdgcn_mfma_f32_16x16x32_bf16(fah[m], fbh[n], acc[m][n], 0, 0, 0);
        __builtin_amdgcn_s_setprio(0);
        __builtin_amdgcn_sched_barrier(0);

        // ---- phase 2: hl ----
        bf16x8 fbl[4];
#pragma unroll
        for (int n = 0; n < 4; ++n) fbl[n] = *(const bf16x8*)(BlL + (wn * 64 + n * 16) * BK + eoff);
        __builtin_amdgcn_s_barrier();
        __builtin_amdgcn_s_setprio(1);
#pragma unroll
        for (int m = 0; m < 4; ++m)
#pragma unroll
            for (int n = 0; n < 4; ++n)
                acc[m][n] = __builtin_amdgcn_mfma_f32_16x16x32_bf16(fah[m], fbl[n], acc[m][n], 0, 0, 0);
        __builtin_amdgcn_s_setprio(0);
        __builtin_amdgcn_sched_barrier(0);

        // ---- phase 3: lh ----
        bf16x8 fal[4];
#pragma unroll
        for (int m = 0; m < 4; ++m) fal[m] = *(const bf16x8*)(AlL + (wm * 64 + m * 16) * BK + eoff);
        __builtin_amdgcn_s_barrier();
        __builtin_amdgcn_s_setprio(1);
#pragma unroll
        for (int m = 0; m < 4; ++m)
#pragma unroll
            for (int n = 0; n < 4; ++n)
                acc[m][n] = __builtin_amdgcn_mfma_f32_16x16x32_bf16(fal[m], fbh[n], acc[m][n], 0, 0, 0);
        __builtin_amdgcn_s_setprio(0);
        __builtin_amdgcn_sched_barrier(0);

        // write next W tile into the other buffer (read next step)
        stageB(nb, nw0, nw1, nmsk);
    }

    // last step (buffer 0)
    asm volatile("s_waitcnt vmcnt(0) lgkmcnt(0)" ::: "memory");
    __builtin_amdgcn_s_barrier();
    asm volatile("" ::: "memory");
    {
        const u16* AhL = Ah[0]; const u16* AlL = Al[0];
        const u16* BhL = Bh[0]; const u16* BlL = Bl[0];
        bf16x8 fah[4], fal[4], fbh[4], fbl[4];
#pragma unroll
        for (int m = 0; m < 4; ++m) {
            const int off = (wm * 64 + m * 16) * BK + eoff;
            fah[m] = *(const bf16x8*)(AhL + off);
            fal[m] = *(const bf16x8*)(AlL + off);
        }
#pragma unroll
        for (int n = 0; n < 4; ++n) {
            const int off = (wn * 64 + n * 16) * BK + eoff;
            fbh[n] = *(const bf16x8*)(BhL + off);
            fbl[n] = *(const bf16x8*)(BlL + off);
        }
#pragma unroll
        for (int m = 0; m < 4; ++m)
#pragma unroll
            for (int n = 0; n < 4; ++n) {
                acc[m][n] = __builtin_amdgcn_mfma_f32_16x16x32_bf16(fah[m], fbh[n], acc[m][n], 0, 0, 0);
                acc[m][n] = __builtin_amdgcn_mfma_f32_16x16x32_bf16(fah[m], fbl[n], acc[m][n], 0, 0, 0);
                acc[m][n] = __builtin_amdgcn_mfma_f32_16x16x32_bf16(fal[m], fbh[n], acc[m][n], 0, 0, 0);
            }
    }

    // epilogue: C/D layout col = lane&15, row = (lane>>4)*4 + reg
    const int rowb = wm * 64 + lc * 4;
    const int colb = n0 + wn * 64 + l15;
#pragma unroll
    for (int m = 0; m < 4; ++m)
#pragma unroll
        for (int n = 0; n < 4; ++n) {
            const size_t base = ((size_t)(ks * NS + rowb + m * 16)) * NP + colb + n * 16;
            Yp[base]          = acc[m][n][0];
            Yp[base + NP]     = acc[m][n][1];
            Yp[base + 2*NP]   = acc[m][n][2];
            Yp[base + 3*NP]   = acc[m][n][3];
        }
}

// ---------------- per-sample: fused (reduce+bias+relu) -> cov -> chol -> w ----------------
// 256 thr. Y staged in LDS; cov tile (8x7 per thread) kept in REGISTERS; Cholesky =
// register-resident symmetric rank-1 updates with LDS column broadcast, 1 barrier/column.
__global__ __launch_bounds__(256, 1) void k_solve(const float* __restrict__ Yp,
                                                  const float* __restrict__ bias,
                                                  float* __restrict__ out)
{
    __shared__ float Ylds[15008];
    __shared__ float Lsh[100 * 105];
    __shared__ float colbuf[2][104];
    __shared__ float mu[100];
    __shared__ float dgi[100];
    __shared__ float sol[104];
    __shared__ float ysol[104];
    __shared__ float gv[104];
    __shared__ float usol[104];
    __shared__ float red[4];

    const int s = blockIdx.x;
    const int t = threadIdx.x;

    // fused split-K reduce + bias + relu into LDS
    const float* y0 = Yp + (size_t)s * NP;
    const float* y1 = Yp + (size_t)(NS + s) * NP;
    for (int o = t; o < 15000; o += 256)
        Ylds[o] = fmaxf(y0[o] + y1[o] + bias[o], 0.f);
    if (t < 8) Ylds[15000 + t] = 0.f;   // keep OOB-row reads finite
    __syncthreads();

    // column means
    if (t < NA) {
        float a = 0.f;
        for (int r = 0; r < COVR; ++r) a += Ylds[r * NA + t];
        mu[t] = a * (1.0f / COVR);
    }
    __syncthreads();
    // center in place
    for (int o = t; o < 15000; o += 256) {
        int c = o % NA;
        Ylds[o] -= mu[c];
    }
    __syncthreads();

    // cov tile in registers: thread (ai,bj) owns rows ai*8..+8, cols bj*7..+7
    const int ai = t >> 4;
    const int bj = t & 15;
    const int r0 = ai * 8;
    const int c0 = bj * 7;
    const bool act = (ai < 13) && (bj < 15);
    float A[8][7];
#pragma unroll
    for (int i = 0; i < 8; ++i)
#pragma unroll
        for (int j = 0; j < 7; ++j) A[i][j] = 0.f;

    if (act) {
        for (int r = 0; r < COVR; ++r) {
            float mi[8], mj[7];
#pragma unroll
            for (int i = 0; i < 8; ++i) mi[i] = Ylds[r * NA + r0 + i];
#pragma unroll
            for (int j = 0; j < 7; ++j) mj[j] = Ylds[r * NA + c0 + j];
#pragma unroll
            for (int i = 0; i < 8; ++i)
#pragma unroll
                for (int j = 0; j < 7; ++j) A[i][j] += mi[i] * mj[j];
        }
#pragma unroll
        for (int i = 0; i < 8; ++i)
#pragma unroll
            for (int j = 0; j < 7; ++j) A[i][j] *= (1.0f / 149.0f);
    }

    // Cholesky: column j broadcast via colbuf (double-buffered), reg rank-1 update
    if (bj == 0 && ai < 13) {
#pragma unroll
        for (int i = 0; i < 8; ++i) colbuf[0][r0 + i] = A[i][0];
    }
    __syncthreads();

    for (int j = 0; j < NA; ++j) {
        const int cb = j & 1;
        const float d = sqrtf(colbuf[cb][j]);
        const float dinv = 1.0f / d;
        if (t == 0) dgi[j] = dinv;

        float Lr[8], Lc[7];
        if (act) {
#pragma unroll
            for (int i = 0; i < 8; ++i) {
                const int row = r0 + i;
                const float cv = colbuf[cb][row];
                Lr[i] = (row > j) ? cv * dinv : (row == j ? d : 0.f);
            }
#pragma unroll
            for (int k = 0; k < 7; ++k) {
                const int col = c0 + k;
                const float cv = colbuf[cb][col];
                Lc[k] = (col > j) ? cv * dinv : (col == j ? d : 0.f);
            }
#pragma unroll
            for (int i = 0; i < 8; ++i)
#pragma unroll
                for (int k = 0; k < 7; ++k) A[i][k] -= Lr[i] * Lc[k];
        }

        // owners of column j store L column (incl diag) for the solves
        const int bjo = j / 7;
        if (bj == bjo && ai < 13) {
#pragma unroll
            for (int i = 0; i < 8; ++i) Lsh[j * 105 + r0 + i] = Lr[i];
        }
        // owners of column j+1 publish its (updated) values
        if (j + 1 < NA) {
            const int bjn = (j + 1) / 7;
            const int jc = (j + 1) - bjn * 7;
            if (bj == bjn && ai < 13) {
#pragma unroll
                for (int i = 0; i < 8; ++i) colbuf[cb ^ 1][r0 + i] = A[i][jc];
            }
        }
        __syncthreads();
    }

    // forward solve L y = 1  (sol = running rhs, ysol = solution)
    if (t < NA) sol[t] = 1.0f;
    __syncthreads();
    for (int j = 0; j < NA; ++j) {
        const float yj = sol[j] * dgi[j];
        if (t == j) ysol[j] = yj;
        if (t > j && t < NA) sol[t] -= Lsh[j * 105 + t] * yj;
        __syncthreads();
    }
    // backward solve L^T u = y
    if (t < NA) gv[t] = ysol[t];
    __syncthreads();
    for (int j = NA - 1; j >= 0; --j) {
        const float uj = gv[j] * dgi[j];
        if (t == j) usol[j] = uj;
        if (t < j) gv[t] -= Lsh[t * 105 + j] * uj;
        __syncthreads();
    }

    // normalize: w = u / sum(u)
    const float uval = (t < NA) ? usol[t] : 0.f;
    float v = uval;
    for (int off = 32; off > 0; off >>= 1) v += __shfl_down(v, off);
    if ((t & 63) == 0) red[t >> 6] = v;
    __syncthreads();
    const float tot = red[0] + red[1] + red[2] + red[3];
    const float inv = 1.0f / tot;
    if (t < NA) out[s * NA + t] = uval * inv;
}

// ---------------- launcher ----------------
extern "C" void kernel_launch(void* const* d_in, const int* in_sizes, int n_in,
                              void* d_out, int out_size, void* d_ws, size_t ws_size,
                              hipStream_t stream)
{
    const float* x     = (const float*)d_in[0];
    const float* gamma = (const float*)d_in[1];
    const float* beta  = (const float*)d_in[2];
    const float* rm    = (const float*)d_in[3];
    const float* rv    = (const float*)d_in[4];
    const float* W     = (const float*)d_in[5];
    const float* b     = (const float*)d_in[6];
    float* out = (float*)d_out;

    char* ws = (char*)d_ws;
    u16*   xnh = (u16*)ws;                              // 5,144,576 B
    u16*   xnl = (u16*)(ws + 5144576);                  // 5,144,576 B
    float* Yp  = (float*)(ws + 10289152);               // 30,932,992 B
    (void)in_sizes; (void)n_in; (void)out_size; (void)ws_size;

    k_prep_x<<<dim3(40, NS), 256, 0, stream>>>(x, gamma, beta, rm, rv, xnh, xnl);
    k_gemm  <<<dim3(NP / BN, 2), 512, 0, stream>>>(xnh, xnl, W, Yp);
    k_solve <<<dim3(NS), 256, 0, stream>>>(Yp, b, out);
}